// Round 10
// baseline (56.405 us; speedup 1.0000x reference)
//
#include <hip/hip_runtime.h>
#include <math.h>

// x[32,3,512,512] f32 -> |1 - mean over (b,h,w) of min over (c, 20x20 window,
// replicate pad pl=9 pr=10)|.
//
// Fused tile kernel (R6 structure) + __launch_bounds__(384, 2) + plain K3.
// Hypothesis being tested: R5/R6's 125us pathology was the compiler's
// occupancy heuristic capping VGPR at 64 (8 waves/SIMD target), demoting
// e[40]/w[35] to scratch (reported VGPR 36..44). min-2-waves/EU caps VGPR
// at 256 instead -> arrays stay in registers. Tell: VGPR_Count >= 90.
// Ticket/fence dropped (R8: ~25us for per-block device-scope fences);
// final reduce is a separate 1-block kernel (~3us, R4-proven).
//
//   phase 1 (t<332): channel-min + horizontal sliding-min(20) straight from
//            global (coalesced float4, clamped aligned base), Gil-Werman
//            run of 16 -> LDS hm[83][66] (column reads exact 2-way = free).
//   phase 2 (t<256): vertical sliding-min(20), Gil-Werman run of 16, f32 sum.
//   K3: 1-block deterministic reduce of 2048 partials -> |1 - mean|.

#define BATCH 32
#define HH 512
#define WW 512
#define CH (HH * WW)
#define NBX 8
#define NBY 8
#define NBLK (NBX * NBY * BATCH)   // 2048
#define NTHR 384
#define LSTR 66                    // LDS row stride in floats

__device__ __forceinline__ float fmin3(float a, float b, float c) {
    return fminf(fminf(a, b), c);
}

__launch_bounds__(NTHR, 2)
__global__ void dark_fused_kernel(const float* __restrict__ x,
                                  float* __restrict__ partials)
{
    __shared__ float hm[83 * LSTR];   // 21912 B
    __shared__ float red[6];

    const int b  = blockIdx.z;
    const int h0 = blockIdx.y * 64;
    const int w0 = blockIdx.x * 64;
    const int t  = threadIdx.x;
    const float* xb = x + (size_t)b * 3 * CH;

    // ---- Phase 1: channel-min + horizontal min(20) -> LDS (one task/thread)
    if (t < 83 * 4) {
        int r = t >> 2;                  // LDS row 0..82
        int q = t & 3;                   // 16-col quad 0..3
        int gr = h0 - 9 + r; gr = gr < 0 ? 0 : (gr > HH - 1 ? HH - 1 : gr);
        int jg0 = w0 + (q << 4);         // global col of first output
        int grun = jg0 >> 4;             // global run index 0..31
        const float* row = xb + gr * WW;
        int cb  = jg0 - 12;
        int cbc = cb < 0 ? 0 : (cb > WW - 40 ? WW - 40 : cb);  // 0 or 472
        const float4* p0 = (const float4*)(row + cbc);
        const float4* p1 = (const float4*)(row + cbc + CH);
        const float4* p2 = (const float4*)(row + cbc + 2 * CH);
        float e[40];
        #pragma unroll
        for (int k = 0; k < 10; ++k) {
            float4 a = p0[k], bb = p1[k], c = p2[k];
            e[4 * k + 0] = fmin3(a.x, bb.x, c.x);
            e[4 * k + 1] = fmin3(a.y, bb.y, c.y);
            e[4 * k + 2] = fmin3(a.z, bb.z, c.z);
            e[4 * k + 3] = fmin3(a.w, bb.w, c.w);
        }
        // w[d] = channel-min at clamped global col (jg0 + d - 9), d=0..34
        float w[35];
        if (grun == 0) {
            #pragma unroll
            for (int d = 0; d < 35; ++d) w[d] = e[d < 9 ? 0 : d - 9];
        } else if (grun == 31) {
            #pragma unroll
            for (int d = 0; d < 35; ++d) w[d] = e[d + 15 > 39 ? 39 : d + 15];
        } else {
            #pragma unroll
            for (int d = 0; d < 35; ++d) w[d] = e[d + 3];
        }
        // Gil-Werman: o[i] = min(w[i..i+19]), i = 0..15
        float suf[20];
        suf[19] = w[19];
        #pragma unroll
        for (int k = 18; k >= 0; --k) suf[k] = fminf(w[k], suf[k + 1]);
        float pre[15];
        pre[0] = w[20];
        #pragma unroll
        for (int k = 1; k < 15; ++k) pre[k] = fminf(pre[k - 1], w[20 + k]);
        float o[16];
        o[0] = suf[0];
        #pragma unroll
        for (int i = 1; i < 16; ++i) o[i] = fminf(suf[i], pre[i - 1]);

        float* dst = &hm[r * LSTR + (q << 4)];
        #pragma unroll
        for (int k = 0; k < 8; ++k)
            *(float2*)(dst + 2 * k) = make_float2(o[2 * k], o[2 * k + 1]);
    }
    __syncthreads();

    // ---- Phase 2: vertical min(20), run of 16 rows (one task/thread) ----
    float sum = 0.f;
    if (t < 256) {
        int j  = t & 63;
        int i0 = (t >> 6) << 4;
        float w[35];
        #pragma unroll
        for (int d = 0; d < 35; ++d) w[d] = hm[(i0 + d) * LSTR + j];
        float suf[20];
        suf[19] = w[19];
        #pragma unroll
        for (int k = 18; k >= 0; --k) suf[k] = fminf(w[k], suf[k + 1]);
        float pre[15];
        pre[0] = w[20];
        #pragma unroll
        for (int k = 1; k < 15; ++k) pre[k] = fminf(pre[k - 1], w[20 + k]);
        sum = suf[0];
        #pragma unroll
        for (int i = 1; i < 16; ++i) sum += fminf(suf[i], pre[i - 1]);
    }

    // ---- Block partial (deterministic) ----
    #pragma unroll
    for (int off = 32; off; off >>= 1) sum += __shfl_down(sum, off);
    if ((t & 63) == 0) red[t >> 6] = sum;
    __syncthreads();
    if (t == 0) {
        float ps = ((red[0] + red[1]) + (red[2] + red[3])) + (red[4] + red[5]);
        int bid = (blockIdx.z * NBY + blockIdx.y) * NBX + blockIdx.x;
        partials[bid] = ps;
    }
}

__launch_bounds__(256)
__global__ void dark_reduce_kernel(const float* __restrict__ partials, int n,
                                   float* __restrict__ out)
{
    __shared__ float red[4];
    int t = threadIdx.x;
    float s = 0.f;
    for (int i = t; i < n; i += 256) s += partials[i];
    #pragma unroll
    for (int off = 32; off; off >>= 1) s += __shfl_down(s, off);
    if ((t & 63) == 0) red[t >> 6] = s;
    __syncthreads();
    if (t == 0) {
        float total = (red[0] + red[1]) + (red[2] + red[3]);
        float mean = total / (float)((long long)BATCH * CH);
        out[0] = fabsf(1.0f - mean);
    }
}

extern "C" void kernel_launch(void* const* d_in, const int* in_sizes, int n_in,
                              void* d_out, int out_size, void* d_ws, size_t ws_size,
                              hipStream_t stream) {
    const float* x = (const float*)d_in[0];
    float* out = (float*)d_out;
    float* partials = (float*)d_ws;   // 2048 f32

    dim3 grid(NBX, NBY, BATCH);       // 8 x 8 x 32 = 2048 blocks
    dark_fused_kernel<<<grid, NTHR, 0, stream>>>(x, partials);
    dark_reduce_kernel<<<1, 256, 0, stream>>>(partials, NBLK, out);
}

// Round 11
// 46.223 us; speedup vs baseline: 1.2203x; 1.2203x over previous
//
#include <hip/hip_runtime.h>
#include <math.h>

// x[32,3,512,512] f32 -> |1 - mean over (b,h,w) of min over (c, 20x20 window,
// replicate pad pl=9 pr=10)|.
//
// Fused tile kernel, ZERO-ALLOCA formulation.
// History: R5/R6/R10 fused variants used float arrays (e[40]/w[35]/suf/pre);
// the compiler left them in scratch (VGPR_Count 36 even with
// __launch_bounds__(384,2) -- promotion failure, not an RA budget issue) ->
// latency-bound 57-65us. R2-style named scalars allocated fine (VGPR 68).
// This version has NO local arrays at all: loads land in 10 named float4s,
// Gil-Werman is a named-scalar suffix chain (s0..s15) + streaming prefix
// emitting outputs immediately. Nothing can be demoted to scratch.
//
//   phase 1 (t<332): channel-min + horizontal sliding-min(20) from global
//            (coalesced float4, clamped aligned base) -> LDS hm[83][66].
//            Edge replicate handled by template<int SH> w(d)=e[clamp(d+SH)].
//   phase 2 (t<256): vertical sliding-min(20) streamed from LDS, f32 sum
//            (exact same op order as the proven split kernel).
//   K3: 1-block deterministic reduce of 2048 partials -> |1 - mean|.
// Do NOT reintroduce: in-graph hipMemsetAsync (R7: ~58us), per-block
// device-scope fences/ticket (R8: +25us).

#define BATCH 32
#define HH 512
#define WW 512
#define CH (HH * WW)
#define NBX 8
#define NBY 8
#define NBLK (NBX * NBY * BATCH)   // 2048
#define NTHR 384
#define LSTR 66                    // LDS row stride in floats

__device__ __forceinline__ float fmin3(float a, float b, float c) {
    return fminf(fminf(a, b), c);
}
__device__ __forceinline__ float4 min34(float4 a, float4 b, float4 c) {
    float4 r;
    r.x = fmin3(a.x, b.x, c.x); r.y = fmin3(a.y, b.y, c.y);
    r.z = fmin3(a.z, b.z, c.z); r.w = fmin3(a.w, b.w, c.w);
    return r;
}

struct M10 { float4 m0, m1, m2, m3, m4, m5, m6, m7, m8, m9; };

__device__ __forceinline__ float comp4(const float4& v, int c) {
    switch (c) { case 0: return v.x; case 1: return v.y;
                 case 2: return v.z; default: return v.w; }
}
// e[i], i = 0..39 -- i is always a compile-time constant at call sites,
// so the switches fold to a direct named-register read.
__device__ __forceinline__ float ec(const M10& M, int i) {
    switch (i >> 2) {
        case 0: return comp4(M.m0, i & 3); case 1: return comp4(M.m1, i & 3);
        case 2: return comp4(M.m2, i & 3); case 3: return comp4(M.m3, i & 3);
        case 4: return comp4(M.m4, i & 3); case 5: return comp4(M.m5, i & 3);
        case 6: return comp4(M.m6, i & 3); case 7: return comp4(M.m7, i & 3);
        case 8: return comp4(M.m8, i & 3); default: return comp4(M.m9, i & 3);
    }
}

// Horizontal Gil-Werman over w(d) = e[clamp(d+SH, 0, 39)], d = 0..34:
//   suf[i] = min(w[i..19]) (named chain), pre streamed; o[i] -> dst[i].
// SH = 3 interior, -9 left-edge run, 15 right-edge run.
template<int SH>
__device__ __forceinline__ void gw16_store(const M10& M, float* dst) {
#define WD(d) ec(M, ((d) + SH) < 0 ? 0 : (((d) + SH) > 39 ? 39 : (d) + SH))
    float s19 = WD(19);
    float s18 = fminf(WD(18), s19);
    float s17 = fminf(WD(17), s18);
    float s16 = fminf(WD(16), s17);
    float s15 = fminf(WD(15), s16);
    float s14 = fminf(WD(14), s15);
    float s13 = fminf(WD(13), s14);
    float s12 = fminf(WD(12), s13);
    float s11 = fminf(WD(11), s12);
    float s10 = fminf(WD(10), s11);
    float s9  = fminf(WD(9),  s10);
    float s8  = fminf(WD(8),  s9);
    float s7  = fminf(WD(7),  s8);
    float s6  = fminf(WD(6),  s7);
    float s5  = fminf(WD(5),  s6);
    float s4  = fminf(WD(4),  s5);
    float s3  = fminf(WD(3),  s4);
    float s2  = fminf(WD(2),  s3);
    float s1  = fminf(WD(1),  s2);
    float s0  = fminf(WD(0),  s1);
    float p = WD(20);
    dst[0]  = s0;
    dst[1]  = fminf(s1, p);
    p = fminf(p, WD(21)); dst[2]  = fminf(s2,  p);
    p = fminf(p, WD(22)); dst[3]  = fminf(s3,  p);
    p = fminf(p, WD(23)); dst[4]  = fminf(s4,  p);
    p = fminf(p, WD(24)); dst[5]  = fminf(s5,  p);
    p = fminf(p, WD(25)); dst[6]  = fminf(s6,  p);
    p = fminf(p, WD(26)); dst[7]  = fminf(s7,  p);
    p = fminf(p, WD(27)); dst[8]  = fminf(s8,  p);
    p = fminf(p, WD(28)); dst[9]  = fminf(s9,  p);
    p = fminf(p, WD(29)); dst[10] = fminf(s10, p);
    p = fminf(p, WD(30)); dst[11] = fminf(s11, p);
    p = fminf(p, WD(31)); dst[12] = fminf(s12, p);
    p = fminf(p, WD(32)); dst[13] = fminf(s13, p);
    p = fminf(p, WD(33)); dst[14] = fminf(s14, p);
    p = fminf(p, WD(34)); dst[15] = fminf(s15, p);
#undef WD
}

__launch_bounds__(NTHR, 2)
__global__ void dark_fused_kernel(const float* __restrict__ x,
                                  float* __restrict__ partials)
{
    __shared__ float hm[83 * LSTR];   // 21912 B
    __shared__ float red[6];

    const int b  = blockIdx.z;
    const int h0 = blockIdx.y * 64;
    const int w0 = blockIdx.x * 64;
    const int t  = threadIdx.x;
    const float* xb = x + (size_t)b * 3 * CH;

    // ---- Phase 1: channel-min + horizontal min(20) -> LDS (one task/thread)
    if (t < 83 * 4) {
        int r = t >> 2;                  // LDS row 0..82
        int q = t & 3;                   // 16-col quad 0..3
        int gr = h0 - 9 + r; gr = gr < 0 ? 0 : (gr > HH - 1 ? HH - 1 : gr);
        int jg0 = w0 + (q << 4);         // global col of first output
        int grun = jg0 >> 4;             // global run index 0..31
        const float* row = xb + gr * WW;
        int cb  = jg0 - 12;
        int cbc = cb < 0 ? 0 : (cb > WW - 40 ? WW - 40 : cb);  // 0 or 472
        const float4* p0 = (const float4*)(row + cbc);
        const float4* p1 = (const float4*)(row + cbc + CH);
        const float4* p2 = (const float4*)(row + cbc + 2 * CH);
        M10 M;
        M.m0 = min34(p0[0], p1[0], p2[0]);
        M.m1 = min34(p0[1], p1[1], p2[1]);
        M.m2 = min34(p0[2], p1[2], p2[2]);
        M.m3 = min34(p0[3], p1[3], p2[3]);
        M.m4 = min34(p0[4], p1[4], p2[4]);
        M.m5 = min34(p0[5], p1[5], p2[5]);
        M.m6 = min34(p0[6], p1[6], p2[6]);
        M.m7 = min34(p0[7], p1[7], p2[7]);
        M.m8 = min34(p0[8], p1[8], p2[8]);
        M.m9 = min34(p0[9], p1[9], p2[9]);

        float* dst = &hm[r * LSTR + (q << 4)];
        if (grun == 0)       gw16_store<-9>(M, dst);   // w[d]=e[max(d-9,0)]
        else if (grun == 31) gw16_store<15>(M, dst);   // w[d]=e[min(d+15,39)]
        else                 gw16_store<3>(M, dst);    // w[d]=e[d+3]
    }
    __syncthreads();

    // ---- Phase 2: vertical min(20), run of 16 rows, streamed from LDS ----
    float sum = 0.f;
    if (t < 256) {
        int j  = t & 63;
        int i0 = (t >> 6) << 4;
        const float* base = &hm[i0 * LSTR + j];
#define HD(d) base[(d) * LSTR]
        float s19 = HD(19);
        float s18 = fminf(HD(18), s19);
        float s17 = fminf(HD(17), s18);
        float s16 = fminf(HD(16), s17);
        float s15 = fminf(HD(15), s16);
        float s14 = fminf(HD(14), s15);
        float s13 = fminf(HD(13), s14);
        float s12 = fminf(HD(12), s13);
        float s11 = fminf(HD(11), s12);
        float s10 = fminf(HD(10), s11);
        float s9  = fminf(HD(9),  s10);
        float s8  = fminf(HD(8),  s9);
        float s7  = fminf(HD(7),  s8);
        float s6  = fminf(HD(6),  s7);
        float s5  = fminf(HD(5),  s6);
        float s4  = fminf(HD(4),  s5);
        float s3  = fminf(HD(3),  s4);
        float s2  = fminf(HD(2),  s3);
        float s1  = fminf(HD(1),  s2);
        float s0  = fminf(HD(0),  s1);
        // exact op order of the proven kernel: sum = suf[0]; += min(suf[i],pre[i-1])
        sum = s0;
        float p = HD(20);
        sum += fminf(s1, p);
        p = fminf(p, HD(21)); sum += fminf(s2,  p);
        p = fminf(p, HD(22)); sum += fminf(s3,  p);
        p = fminf(p, HD(23)); sum += fminf(s4,  p);
        p = fminf(p, HD(24)); sum += fminf(s5,  p);
        p = fminf(p, HD(25)); sum += fminf(s6,  p);
        p = fminf(p, HD(26)); sum += fminf(s7,  p);
        p = fminf(p, HD(27)); sum += fminf(s8,  p);
        p = fminf(p, HD(28)); sum += fminf(s9,  p);
        p = fminf(p, HD(29)); sum += fminf(s10, p);
        p = fminf(p, HD(30)); sum += fminf(s11, p);
        p = fminf(p, HD(31)); sum += fminf(s12, p);
        p = fminf(p, HD(32)); sum += fminf(s13, p);
        p = fminf(p, HD(33)); sum += fminf(s14, p);
        p = fminf(p, HD(34)); sum += fminf(s15, p);
#undef HD
    }

    // ---- Block partial (deterministic) ----
    #pragma unroll
    for (int off = 32; off; off >>= 1) sum += __shfl_down(sum, off);
    if ((t & 63) == 0) red[t >> 6] = sum;
    __syncthreads();
    if (t == 0) {
        float ps = ((red[0] + red[1]) + (red[2] + red[3])) + (red[4] + red[5]);
        int bid = (blockIdx.z * NBY + blockIdx.y) * NBX + blockIdx.x;
        partials[bid] = ps;
    }
}

__launch_bounds__(256)
__global__ void dark_reduce_kernel(const float* __restrict__ partials, int n,
                                   float* __restrict__ out)
{
    __shared__ float red[4];
    int t = threadIdx.x;
    float s = 0.f;
    for (int i = t; i < n; i += 256) s += partials[i];
    #pragma unroll
    for (int off = 32; off; off >>= 1) s += __shfl_down(s, off);
    if ((t & 63) == 0) red[t >> 6] = s;
    __syncthreads();
    if (t == 0) {
        float total = (red[0] + red[1]) + (red[2] + red[3]);
        float mean = total / (float)((long long)BATCH * CH);
        out[0] = fabsf(1.0f - mean);
    }
}

extern "C" void kernel_launch(void* const* d_in, const int* in_sizes, int n_in,
                              void* d_out, int out_size, void* d_ws, size_t ws_size,
                              hipStream_t stream) {
    const float* x = (const float*)d_in[0];
    float* out = (float*)d_out;
    float* partials = (float*)d_ws;   // 2048 f32

    dim3 grid(NBX, NBY, BATCH);       // 8 x 8 x 32 = 2048 blocks
    dark_fused_kernel<<<grid, NTHR, 0, stream>>>(x, partials);
    dark_reduce_kernel<<<1, 256, 0, stream>>>(partials, NBLK, out);
}

// Round 12
// 45.295 us; speedup vs baseline: 1.2453x; 1.0205x over previous
//
#include <hip/hip_runtime.h>
#include <math.h>

// x[32,3,512,512] f32 -> |1 - mean over (b,h,w) of min over (c, 20x20 window,
// replicate pad pl=9 pr=10)|.
//
// Fused tile kernel, zero-alloca + occupancy-targeted launch_bounds.
// Ledger of the fused line:
//   R5/R6: float arrays -> scratch demotion (VGPR 36..44), ~125us.
//   R10: arrays + __launch_bounds__(384,2): still VGPR 36 (promotion
//        failure, not RA budget), 56us.
//   R11: zero-alloca (named float4s + scalar chains) + (384,2): no scratch,
//        but RA budget 256 VGPR -> likely >128 used -> 2 waves/SIMD ->
//        ONE 6-wave block/CU -> latency-bound, 46us total.
//   R12 (this): (384,4) caps RA at 128 VGPR -- working set ~70-90 live regs
//        fits -> 4 waves/SIMD -> 2 blocks (12 waves)/CU. Tell: VGPR in
//        (64,128], total ~26-31us. If >=36.5us, fused line is dead; revert
//        to R9 split.
// Do NOT reintroduce: in-graph hipMemsetAsync (R7: ~58us/replay), per-block
// device-scope fences/ticket (R8: +25us).
//
//   phase 1 (t<332): channel-min + horizontal sliding-min(20) from global
//            (coalesced float4, clamped aligned base) -> LDS hm[83][66]
//            (write banks exact 2-way = free; column reads 2-way = free).
//   phase 2 (t<256): vertical sliding-min(20) streamed from LDS, f32 sum
//            (exact op order of the proven split kernel).
//   K3: 1-block deterministic reduce of 2048 partials -> |1 - mean|.

#define BATCH 32
#define HH 512
#define WW 512
#define CH (HH * WW)
#define NBX 8
#define NBY 8
#define NBLK (NBX * NBY * BATCH)   // 2048
#define NTHR 384
#define LSTR 66                    // LDS row stride in floats

__device__ __forceinline__ float fmin3(float a, float b, float c) {
    return fminf(fminf(a, b), c);
}
__device__ __forceinline__ float4 min34(float4 a, float4 b, float4 c) {
    float4 r;
    r.x = fmin3(a.x, b.x, c.x); r.y = fmin3(a.y, b.y, c.y);
    r.z = fmin3(a.z, b.z, c.z); r.w = fmin3(a.w, b.w, c.w);
    return r;
}

struct M10 { float4 m0, m1, m2, m3, m4, m5, m6, m7, m8, m9; };

__device__ __forceinline__ float comp4(const float4& v, int c) {
    switch (c) { case 0: return v.x; case 1: return v.y;
                 case 2: return v.z; default: return v.w; }
}
// e[i], i = 0..39 -- i is always a compile-time constant at call sites,
// so the switches fold to a direct named-register read.
__device__ __forceinline__ float ec(const M10& M, int i) {
    switch (i >> 2) {
        case 0: return comp4(M.m0, i & 3); case 1: return comp4(M.m1, i & 3);
        case 2: return comp4(M.m2, i & 3); case 3: return comp4(M.m3, i & 3);
        case 4: return comp4(M.m4, i & 3); case 5: return comp4(M.m5, i & 3);
        case 6: return comp4(M.m6, i & 3); case 7: return comp4(M.m7, i & 3);
        case 8: return comp4(M.m8, i & 3); default: return comp4(M.m9, i & 3);
    }
}

// Horizontal Gil-Werman over w(d) = e[clamp(d+SH, 0, 39)], d = 0..34:
//   suf[i] = min(w[i..19]) (named chain), pre streamed; o[i] -> dst[i].
// SH = 3 interior, -9 left-edge run, 15 right-edge run.
template<int SH>
__device__ __forceinline__ void gw16_store(const M10& M, float* dst) {
#define WD(d) ec(M, ((d) + SH) < 0 ? 0 : (((d) + SH) > 39 ? 39 : (d) + SH))
    float s19 = WD(19);
    float s18 = fminf(WD(18), s19);
    float s17 = fminf(WD(17), s18);
    float s16 = fminf(WD(16), s17);
    float s15 = fminf(WD(15), s16);
    float s14 = fminf(WD(14), s15);
    float s13 = fminf(WD(13), s14);
    float s12 = fminf(WD(12), s13);
    float s11 = fminf(WD(11), s12);
    float s10 = fminf(WD(10), s11);
    float s9  = fminf(WD(9),  s10);
    float s8  = fminf(WD(8),  s9);
    float s7  = fminf(WD(7),  s8);
    float s6  = fminf(WD(6),  s7);
    float s5  = fminf(WD(5),  s6);
    float s4  = fminf(WD(4),  s5);
    float s3  = fminf(WD(3),  s4);
    float s2  = fminf(WD(2),  s3);
    float s1  = fminf(WD(1),  s2);
    float s0  = fminf(WD(0),  s1);
    float p = WD(20);
    dst[0]  = s0;
    dst[1]  = fminf(s1, p);
    p = fminf(p, WD(21)); dst[2]  = fminf(s2,  p);
    p = fminf(p, WD(22)); dst[3]  = fminf(s3,  p);
    p = fminf(p, WD(23)); dst[4]  = fminf(s4,  p);
    p = fminf(p, WD(24)); dst[5]  = fminf(s5,  p);
    p = fminf(p, WD(25)); dst[6]  = fminf(s6,  p);
    p = fminf(p, WD(26)); dst[7]  = fminf(s7,  p);
    p = fminf(p, WD(27)); dst[8]  = fminf(s8,  p);
    p = fminf(p, WD(28)); dst[9]  = fminf(s9,  p);
    p = fminf(p, WD(29)); dst[10] = fminf(s10, p);
    p = fminf(p, WD(30)); dst[11] = fminf(s11, p);
    p = fminf(p, WD(31)); dst[12] = fminf(s12, p);
    p = fminf(p, WD(32)); dst[13] = fminf(s13, p);
    p = fminf(p, WD(33)); dst[14] = fminf(s14, p);
    p = fminf(p, WD(34)); dst[15] = fminf(s15, p);
#undef WD
}

__launch_bounds__(NTHR, 4)
__global__ void dark_fused_kernel(const float* __restrict__ x,
                                  float* __restrict__ partials)
{
    __shared__ float hm[83 * LSTR];   // 21912 B
    __shared__ float red[6];

    const int b  = blockIdx.z;
    const int h0 = blockIdx.y * 64;
    const int w0 = blockIdx.x * 64;
    const int t  = threadIdx.x;
    const float* xb = x + (size_t)b * 3 * CH;

    // ---- Phase 1: channel-min + horizontal min(20) -> LDS (one task/thread)
    if (t < 83 * 4) {
        int r = t >> 2;                  // LDS row 0..82
        int q = t & 3;                   // 16-col quad 0..3
        int gr = h0 - 9 + r; gr = gr < 0 ? 0 : (gr > HH - 1 ? HH - 1 : gr);
        int jg0 = w0 + (q << 4);         // global col of first output
        int grun = jg0 >> 4;             // global run index 0..31
        const float* row = xb + gr * WW;
        int cb  = jg0 - 12;
        int cbc = cb < 0 ? 0 : (cb > WW - 40 ? WW - 40 : cb);  // 0 or 472
        const float4* p0 = (const float4*)(row + cbc);
        const float4* p1 = (const float4*)(row + cbc + CH);
        const float4* p2 = (const float4*)(row + cbc + 2 * CH);
        M10 M;
        M.m0 = min34(p0[0], p1[0], p2[0]);
        M.m1 = min34(p0[1], p1[1], p2[1]);
        M.m2 = min34(p0[2], p1[2], p2[2]);
        M.m3 = min34(p0[3], p1[3], p2[3]);
        M.m4 = min34(p0[4], p1[4], p2[4]);
        M.m5 = min34(p0[5], p1[5], p2[5]);
        M.m6 = min34(p0[6], p1[6], p2[6]);
        M.m7 = min34(p0[7], p1[7], p2[7]);
        M.m8 = min34(p0[8], p1[8], p2[8]);
        M.m9 = min34(p0[9], p1[9], p2[9]);

        float* dst = &hm[r * LSTR + (q << 4)];
        if (grun == 0)       gw16_store<-9>(M, dst);   // w[d]=e[max(d-9,0)]
        else if (grun == 31) gw16_store<15>(M, dst);   // w[d]=e[min(d+15,39)]
        else                 gw16_store<3>(M, dst);    // w[d]=e[d+3]
    }
    __syncthreads();

    // ---- Phase 2: vertical min(20), run of 16 rows, streamed from LDS ----
    float sum = 0.f;
    if (t < 256) {
        int j  = t & 63;
        int i0 = (t >> 6) << 4;
        const float* base = &hm[i0 * LSTR + j];
#define HD(d) base[(d) * LSTR]
        float s19 = HD(19);
        float s18 = fminf(HD(18), s19);
        float s17 = fminf(HD(17), s18);
        float s16 = fminf(HD(16), s17);
        float s15 = fminf(HD(15), s16);
        float s14 = fminf(HD(14), s15);
        float s13 = fminf(HD(13), s14);
        float s12 = fminf(HD(12), s13);
        float s11 = fminf(HD(11), s12);
        float s10 = fminf(HD(10), s11);
        float s9  = fminf(HD(9),  s10);
        float s8  = fminf(HD(8),  s9);
        float s7  = fminf(HD(7),  s8);
        float s6  = fminf(HD(6),  s7);
        float s5  = fminf(HD(5),  s6);
        float s4  = fminf(HD(4),  s5);
        float s3  = fminf(HD(3),  s4);
        float s2  = fminf(HD(2),  s3);
        float s1  = fminf(HD(1),  s2);
        float s0  = fminf(HD(0),  s1);
        // exact op order of the proven kernel: sum = suf[0]; += min(suf[i],pre[i-1])
        sum = s0;
        float p = HD(20);
        sum += fminf(s1, p);
        p = fminf(p, HD(21)); sum += fminf(s2,  p);
        p = fminf(p, HD(22)); sum += fminf(s3,  p);
        p = fminf(p, HD(23)); sum += fminf(s4,  p);
        p = fminf(p, HD(24)); sum += fminf(s5,  p);
        p = fminf(p, HD(25)); sum += fminf(s6,  p);
        p = fminf(p, HD(26)); sum += fminf(s7,  p);
        p = fminf(p, HD(27)); sum += fminf(s8,  p);
        p = fminf(p, HD(28)); sum += fminf(s9,  p);
        p = fminf(p, HD(29)); sum += fminf(s10, p);
        p = fminf(p, HD(30)); sum += fminf(s11, p);
        p = fminf(p, HD(31)); sum += fminf(s12, p);
        p = fminf(p, HD(32)); sum += fminf(s13, p);
        p = fminf(p, HD(33)); sum += fminf(s14, p);
        p = fminf(p, HD(34)); sum += fminf(s15, p);
#undef HD
    }

    // ---- Block partial (deterministic) ----
    #pragma unroll
    for (int off = 32; off; off >>= 1) sum += __shfl_down(sum, off);
    if ((t & 63) == 0) red[t >> 6] = sum;
    __syncthreads();
    if (t == 0) {
        float ps = ((red[0] + red[1]) + (red[2] + red[3])) + (red[4] + red[5]);
        int bid = (blockIdx.z * NBY + blockIdx.y) * NBX + blockIdx.x;
        partials[bid] = ps;
    }
}

__launch_bounds__(256)
__global__ void dark_reduce_kernel(const float* __restrict__ partials, int n,
                                   float* __restrict__ out)
{
    __shared__ float red[4];
    int t = threadIdx.x;
    float s = 0.f;
    for (int i = t; i < n; i += 256) s += partials[i];
    #pragma unroll
    for (int off = 32; off; off >>= 1) s += __shfl_down(s, off);
    if ((t & 63) == 0) red[t >> 6] = s;
    __syncthreads();
    if (t == 0) {
        float total = (red[0] + red[1]) + (red[2] + red[3]);
        float mean = total / (float)((long long)BATCH * CH);
        out[0] = fabsf(1.0f - mean);
    }
}

extern "C" void kernel_launch(void* const* d_in, const int* in_sizes, int n_in,
                              void* d_out, int out_size, void* d_ws, size_t ws_size,
                              hipStream_t stream) {
    const float* x = (const float*)d_in[0];
    float* out = (float*)d_out;
    float* partials = (float*)d_ws;   // 2048 f32

    dim3 grid(NBX, NBY, BATCH);       // 8 x 8 x 32 = 2048 blocks
    dark_fused_kernel<<<grid, NTHR, 0, stream>>>(x, partials);
    dark_reduce_kernel<<<1, 256, 0, stream>>>(partials, NBLK, out);
}